// Round 1
// baseline (222.709 us; speedup 1.0000x reference)
//
#include <hip/hip_runtime.h>
#include <math.h>

#define B_ 2
#define T_ 8
#define N_ 2048
#define F_ 64
#define ROWS_PB 16   // rows per block in wh_kernel
#define TI 8         // i-rows per block in main kernel
#define JC 64        // j-chunk

// ---------------- Kernel A: Wh = h @ W ; Wh1 = Wh @ a[:64]; Wh2 = Wh @ a[64:]
__global__ __launch_bounds__(256) void wh_kernel(
    const float* __restrict__ h, const float* __restrict__ W,
    const float* __restrict__ a, float* __restrict__ Wh,
    float* __restrict__ Wh1, float* __restrict__ Wh2) {
  __shared__ float Ws[64][64];        // 16KB
  __shared__ float hs[ROWS_PB][64];   // 4KB
  const int tid = threadIdx.x;
  const int row0 = blockIdx.x * ROWS_PB;
  for (int i = tid; i < 64 * 64; i += 256) Ws[i >> 6][i & 63] = W[i];
  for (int i = tid; i < ROWS_PB * 64; i += 256) hs[i >> 6][i & 63] = h[(size_t)row0 * 64 + i];
  __syncthreads();
  const int f = tid & 63;     // feature
  const int wr = tid >> 6;    // wave id 0..3
  const float af1 = a[f];
  const float af2 = a[64 + f];
  for (int r = wr; r < ROWS_PB; r += 4) {
    float acc = 0.f;
#pragma unroll
    for (int k = 0; k < 64; ++k) acc = fmaf(hs[r][k], Ws[k][f], acc);
    Wh[(size_t)(row0 + r) * 64 + f] = acc;
    float p1 = acc * af1;
    float p2 = acc * af2;
#pragma unroll
    for (int off = 32; off; off >>= 1) {
      p1 += __shfl_down(p1, off);
      p2 += __shfl_down(p2, off);
    }
    if (f == 0) {
      Wh1[row0 + r] = p1;
      Wh2[row0 + r] = p2;
    }
  }
}

// ---------------- Kernel B: fused attention (softmax over T axis!) + PV + ELU
// out[b,t,i,f] = ELU( sum_j att[b,t,i,j] * Wh[b,t,j,f] )
// att over t: softmax_t( leakyrelu(Wh1[b,t,i]+Wh2[b,t,j]) ) if adj[i,j]>0 else 1/8
__global__ __launch_bounds__(256) void gat_main(
    const float* __restrict__ Wh, const float* __restrict__ Wh1,
    const float* __restrict__ Wh2, const int* __restrict__ adj,
    float* __restrict__ out) {
  __shared__ float wh1s[T_][TI];                              // 256B
  __shared__ float wh2s[T_][JC];                              // 2KB
  __shared__ int adjs[TI][JC];                                // 2KB
  __shared__ __attribute__((aligned(16))) float atts[T_][TI][JC];  // 16KB
  const int tid = threadIdx.x;
  const int b = blockIdx.x >> 8;            // N_/TI = 256 tiles per batch
  const int i0 = (blockIdx.x & 255) * TI;

  if (tid < T_ * TI) {
    const int tt = tid >> 3;   // TI == 8
    const int ii = tid & 7;
    wh1s[tt][ii] = Wh1[(size_t)(b * T_ + tt) * N_ + i0 + ii];
  }

  const int t = tid >> 5;      // 0..7
  const int fh = tid & 31;     // feature half-index; handles f=fh and f=fh+32
  float acc[TI][2];
#pragma unroll
  for (int ii = 0; ii < TI; ++ii) { acc[ii][0] = 0.f; acc[ii][1] = 0.f; }

  const float* whbase = Wh + (size_t)(b * T_ + t) * N_ * F_;

  for (int j0 = 0; j0 < N_; j0 += JC) {
    __syncthreads();  // previous accumulate done (atts free), wh1s staged
    // ---- stage Wh2 chunk [T_][JC] and adj chunk [TI][JC]
    for (int x = tid; x < T_ * JC; x += 256) {
      const int tt = x >> 6, jj = x & 63;
      wh2s[tt][jj] = Wh2[(size_t)(b * T_ + tt) * N_ + j0 + jj];
    }
    for (int x = tid; x < TI * JC; x += 256) {
      const int ii = x >> 6, jj = x & 63;
      adjs[ii][jj] = adj[(size_t)(i0 + ii) * N_ + j0 + jj];
    }
    __syncthreads();
    // ---- compute attention weights for TI*JC pairs (softmax over the 8 t's)
    for (int p = tid; p < TI * JC; p += 256) {
      const int ii = p >> 6, jj = p & 63;
      if (adjs[ii][jj] > 0) {
        float v[T_];
        float m = -1e30f;
#pragma unroll
        for (int tt = 0; tt < T_; ++tt) {
          float e = wh1s[tt][ii] + wh2s[tt][jj];
          e = e > 0.f ? e : 0.2f * e;   // LeakyReLU
          v[tt] = e;
          m = fmaxf(m, e);
        }
        float s = 0.f;
#pragma unroll
        for (int tt = 0; tt < T_; ++tt) {
          const float ex = __expf(v[tt] - m);
          v[tt] = ex;
          s += ex;
        }
        const float r = 1.0f / s;
#pragma unroll
        for (int tt = 0; tt < T_; ++tt) atts[tt][ii][jj] = v[tt] * r;
      } else {
        // all 8 scores are NEG_INF -> softmax over t is uniform 1/8
#pragma unroll
        for (int tt = 0; tt < T_; ++tt) atts[tt][ii][jj] = 0.125f;
      }
    }
    __syncthreads();
    // ---- accumulate: acc[ii][.] += att[t][ii][jj] * Wh[b,t,j0+jj,f]
    const float* whp = whbase + (size_t)j0 * F_;
#pragma unroll 2
    for (int jj4 = 0; jj4 < JC; jj4 += 4) {
      const float w00 = whp[(jj4 + 0) * 64 + fh];
      const float w01 = whp[(jj4 + 1) * 64 + fh];
      const float w02 = whp[(jj4 + 2) * 64 + fh];
      const float w03 = whp[(jj4 + 3) * 64 + fh];
      const float w10 = whp[(jj4 + 0) * 64 + fh + 32];
      const float w11 = whp[(jj4 + 1) * 64 + fh + 32];
      const float w12 = whp[(jj4 + 2) * 64 + fh + 32];
      const float w13 = whp[(jj4 + 3) * 64 + fh + 32];
#pragma unroll
      for (int ii = 0; ii < TI; ++ii) {
        const float4 av = *reinterpret_cast<const float4*>(&atts[t][ii][jj4]);
        acc[ii][0] = fmaf(av.x, w00, acc[ii][0]);
        acc[ii][0] = fmaf(av.y, w01, acc[ii][0]);
        acc[ii][0] = fmaf(av.z, w02, acc[ii][0]);
        acc[ii][0] = fmaf(av.w, w03, acc[ii][0]);
        acc[ii][1] = fmaf(av.x, w10, acc[ii][1]);
        acc[ii][1] = fmaf(av.y, w11, acc[ii][1]);
        acc[ii][1] = fmaf(av.z, w12, acc[ii][1]);
        acc[ii][1] = fmaf(av.w, w13, acc[ii][1]);
      }
    }
  }

  // ---- epilogue: ELU + store
  float* op = out + ((size_t)(b * T_ + t) * N_ + i0) * F_;
#pragma unroll
  for (int ii = 0; ii < TI; ++ii) {
    const float x0 = acc[ii][0];
    const float x1 = acc[ii][1];
    op[ii * 64 + fh]      = x0 > 0.f ? x0 : expm1f(x0);
    op[ii * 64 + fh + 32] = x1 > 0.f ? x1 : expm1f(x1);
  }
}

extern "C" void kernel_launch(void* const* d_in, const int* in_sizes, int n_in,
                              void* d_out, int out_size, void* d_ws, size_t ws_size,
                              hipStream_t stream) {
  const float* h   = (const float*)d_in[0];
  const float* W   = (const float*)d_in[1];
  const float* a   = (const float*)d_in[2];
  const int*   adj = (const int*)d_in[3];
  float* out = (float*)d_out;

  // workspace layout: Wh [B*T*N*F] fp32, Wh1 [B*T*N], Wh2 [B*T*N]  (~9.4 MB)
  float* Wh  = (float*)d_ws;
  float* Wh1 = Wh + (size_t)B_ * T_ * N_ * F_;
  float* Wh2 = Wh1 + (size_t)B_ * T_ * N_;

  hipLaunchKernelGGL(wh_kernel, dim3(B_ * T_ * N_ / ROWS_PB), dim3(256), 0, stream,
                     h, W, a, Wh, Wh1, Wh2);
  hipLaunchKernelGGL(gat_main, dim3(B_ * (N_ / TI)), dim3(256), 0, stream,
                     Wh, Wh1, Wh2, adj, out);
}

// Round 2
// 100.044 us; speedup vs baseline: 2.2261x; 2.2261x over previous
//
#include <hip/hip_runtime.h>
#include <math.h>

#define B_ 2
#define T_ 8
#define N_ 2048
#define F_ 64
#define TI 16
#define JC 64
#define JCP 72

typedef __attribute__((ext_vector_type(8))) short short8;
typedef __attribute__((ext_vector_type(4))) float f32x4;

__device__ __forceinline__ unsigned short f2bf(float x) {
  unsigned u = __float_as_uint(x);
  u += 0x7FFFu + ((u >> 16) & 1u);
  return (unsigned short)(u >> 16);
}

// ---------------- prep: Wh = h@W (fp32), emit WhT bf16 [bt][f][j], Wh1/Wh2 fp32
__global__ __launch_bounds__(256) void prep_kernel(
    const float* __restrict__ h, const float* __restrict__ W,
    const float* __restrict__ a, unsigned short* __restrict__ WhT,
    float* __restrict__ Wh1, float* __restrict__ Wh2) {
  __shared__ float Ws[64][64];
  __shared__ float hs[64][64];
  __shared__ float Whs[64][65];
  const int tid = threadIdx.x;
  const int row0 = blockIdx.x * 64;   // row in flattened [B*T*N]
  const int bt = row0 >> 11;
  const int j0 = row0 & 2047;
  for (int i = tid; i < 4096; i += 256) Ws[i >> 6][i & 63] = W[i];
  for (int i = tid; i < 4096; i += 256) hs[i >> 6][i & 63] = h[(size_t)row0 * 64 + i];
  __syncthreads();
  const int f = tid & 63;
  const int rq = tid >> 6;            // wave id 0..3 -> rows rq*16..rq*16+15
  float acc[16];
#pragma unroll
  for (int m = 0; m < 16; ++m) acc[m] = 0.f;
#pragma unroll 4
  for (int k = 0; k < 64; ++k) {
    const float wvv = Ws[k][f];
#pragma unroll
    for (int m = 0; m < 16; ++m) acc[m] = fmaf(hs[rq * 16 + m][k], wvv, acc[m]);
  }
#pragma unroll
  for (int m = 0; m < 16; ++m) Whs[rq * 16 + m][f] = acc[m];
  __syncthreads();
  // Wh1/Wh2: thread -> (r = tid>>2, q = tid&3), quad shuffle reduce
  {
    const int r = tid >> 2, q = tid & 3;
    float s1 = 0.f, s2 = 0.f;
#pragma unroll
    for (int k = 0; k < 16; ++k) {
      const float v = Whs[r][q * 16 + k];
      s1 = fmaf(v, a[q * 16 + k], s1);
      s2 = fmaf(v, a[64 + q * 16 + k], s2);
    }
    s1 += __shfl_xor(s1, 1); s1 += __shfl_xor(s1, 2);
    s2 += __shfl_xor(s2, 1); s2 += __shfl_xor(s2, 2);
    if (q == 0) {
      Wh1[(size_t)bt * N_ + j0 + r] = s1;
      Wh2[(size_t)bt * N_ + j0 + r] = s2;
    }
  }
  // WhT store: thread (f, cp = tid>>6): two 8-j groups, packed bf16x8 16B stores
  {
    const int ff = tid & 63, cp = tid >> 6;
#pragma unroll
    for (int cc = 0; cc < 2; ++cc) {
      const int c = cp * 2 + cc;
      short8 v;
#pragma unroll
      for (int k = 0; k < 8; ++k) v[k] = (short)f2bf(Whs[c * 8 + k][ff]);
      *(short8*)(WhT + ((size_t)bt * 64 + ff) * N_ + j0 + c * 8) = v;
    }
  }
}

// ---------------- main: softmax-over-T attention + MFMA PV + ELU
__global__ __launch_bounds__(512) void gat_mfma(
    const unsigned short* __restrict__ WhT, const float* __restrict__ Wh1,
    const float* __restrict__ Wh2, const int* __restrict__ adj,
    float* __restrict__ out) {
  __shared__ unsigned short atts[2][T_][TI][JCP];  // bf16 att tiles, dbuf
  __shared__ float wh1s[T_][TI];
  const int tid = threadIdx.x;
  const int b = blockIdx.x >> 7;            // N_/TI = 128 tiles per batch
  const int i0 = (blockIdx.x & 127) * TI;

  if (tid < T_ * TI) {
    const int t = tid >> 4, ii = tid & 15;
    wh1s[t][ii] = Wh1[(size_t)(b * T_ + t) * N_ + i0 + ii];
  }
  __syncthreads();

  const int wv = tid >> 6;        // wave id == t (0..7)
  const int lane = tid & 63;
  const int col = lane & 15;      // n-col (B) / i-row (A) / out col
  const int kg = lane >> 4;       // k lane-group 0..3

  // softmax work assignment: 2 adjacent j-columns per thread
  const int sii = tid >> 5;          // 0..15
  const int sjj = (tid & 31) * 2;    // 0,2,..,62

  const unsigned short* wtb = WhT + (size_t)(b * T_ + wv) * F_ * N_;
  const float* wh2b = Wh2 + (size_t)b * T_ * N_;
  const int* adjrow = adj + (size_t)(i0 + sii) * N_;

  f32x4 acc[4];
#pragma unroll
  for (int nt = 0; nt < 4; ++nt) acc[nt] = {0.f, 0.f, 0.f, 0.f};

  for (int c = 0; c < N_ / JC; ++c) {
    const int j0 = c * JC;
    const int buf = c & 1;
    // --- issue B-fragment global loads early (independent of atts)
    short8 breg[4][2];
#pragma unroll
    for (int nt = 0; nt < 4; ++nt)
#pragma unroll
      for (int ks = 0; ks < 2; ++ks)
        breg[nt][ks] = *(const short8*)(wtb + (size_t)(nt * 16 + col) * N_ +
                                        j0 + ks * 32 + kg * 8);

    // --- softmax over T for columns (sjj, sjj+1), row sii
    {
      const int2 ad = *(const int2*)(adjrow + j0 + sjj);
      float e0[T_], e1[T_];
      float m0 = -1e30f, m1 = -1e30f;
#pragma unroll
      for (int t = 0; t < T_; ++t) {
        const float2 w2 = *(const float2*)(wh2b + (size_t)t * N_ + j0 + sjj);
        const float w1 = wh1s[t][sii];
        float x0 = w1 + w2.x;
        float x1 = w1 + w2.y;
        x0 = fmaxf(x0, 0.2f * x0);   // LeakyReLU (alpha=0.2 < 1)
        x1 = fmaxf(x1, 0.2f * x1);
        e0[t] = x0; e1[t] = x1;
        m0 = fmaxf(m0, x0); m1 = fmaxf(m1, x1);
      }
      float s0 = 0.f, s1 = 0.f;
#pragma unroll
      for (int t = 0; t < T_; ++t) {
        e0[t] = __expf(e0[t] - m0); s0 += e0[t];
        e1[t] = __expf(e1[t] - m1); s1 += e1[t];
      }
      const float r0 = 1.0f / s0, r1 = 1.0f / s1;
#pragma unroll
      for (int t = 0; t < T_; ++t) {
        // adj==0 -> all 8 scores are NEG_INF -> softmax over t is uniform 1/8
        const float a0 = ad.x > 0 ? e0[t] * r0 : 0.125f;
        const float a1 = ad.y > 0 ? e1[t] * r1 : 0.125f;
        const unsigned pk = (unsigned)f2bf(a0) | ((unsigned)f2bf(a1) << 16);
        *(unsigned*)&atts[buf][t][sii][sjj] = pk;
      }
    }
    __syncthreads();
    // --- MFMA phase: A = att[16i x 64j] (bf16), B = Wh[64j x 64f] (bf16)
    const unsigned short* ab = &atts[buf][wv][col][kg * 8];
    const short8 a0 = *(const short8*)ab;          // k-step 0 (j0.. j0+31)
    const short8 a1 = *(const short8*)(ab + 32);   // k-step 1
#pragma unroll
    for (int nt = 0; nt < 4; ++nt) {
      acc[nt] = __builtin_amdgcn_mfma_f32_16x16x32_bf16(a0, breg[nt][0], acc[nt], 0, 0, 0);
      acc[nt] = __builtin_amdgcn_mfma_f32_16x16x32_bf16(a1, breg[nt][1], acc[nt], 0, 0, 0);
    }
    // NOTE: single barrier per chunk is safe: softmax(c+2) reuses this buf but
    // only starts after barrier(c+1), which follows all waves' MFMA(c) reads.
  }

  // ---- epilogue: ELU + store. C/D: col=lane&15, row=(lane>>4)*4+reg
  float* ob = out + ((size_t)(b * T_ + wv) * N_ + i0) * F_;
#pragma unroll
  for (int nt = 0; nt < 4; ++nt) {
#pragma unroll
    for (int r = 0; r < 4; ++r) {
      const int row = kg * 4 + r;
      const float x = acc[nt][r];
      ob[(size_t)row * F_ + nt * 16 + col] = x > 0.f ? x : expm1f(x);
    }
  }
}

extern "C" void kernel_launch(void* const* d_in, const int* in_sizes, int n_in,
                              void* d_out, int out_size, void* d_ws, size_t ws_size,
                              hipStream_t stream) {
  const float* h   = (const float*)d_in[0];
  const float* W   = (const float*)d_in[1];
  const float* a   = (const float*)d_in[2];
  const int*   adj = (const int*)d_in[3];
  float* out = (float*)d_out;

  // ws: WhT bf16 [B*T*F*N] (4MB), Wh1 fp32 [B*T*N], Wh2 fp32 [B*T*N]
  unsigned short* WhT = (unsigned short*)d_ws;
  float* Wh1 = (float*)((char*)d_ws + (size_t)B_ * T_ * F_ * N_ * 2);
  float* Wh2 = Wh1 + (size_t)B_ * T_ * N_;

  hipLaunchKernelGGL(prep_kernel, dim3(B_ * T_ * N_ / 64), dim3(256), 0, stream,
                     h, W, a, WhT, Wh1, Wh2);
  hipLaunchKernelGGL(gat_mfma, dim3(B_ * (N_ / TI)), dim3(512), 0, stream,
                     WhT, Wh1, Wh2, adj, out);
}

// Round 3
// 87.265 us; speedup vs baseline: 2.5521x; 1.1464x over previous
//
#include <hip/hip_runtime.h>
#include <math.h>

#define B_ 2
#define T_ 8
#define N_ 2048
#define F_ 64
#define TI 16
#define JC 64
#define JCP 72
#define LOG2E 1.44269504088896f

typedef __attribute__((ext_vector_type(8))) short short8;
typedef __attribute__((ext_vector_type(4))) float f32x4;

__device__ __forceinline__ unsigned short f2bf(float x) {
  unsigned u = __float_as_uint(x);
  u += 0x7FFFu + ((u >> 16) & 1u);
  return (unsigned short)(u >> 16);
}

__device__ __forceinline__ unsigned cvt_pk_bf16(float lo, float hi) {
  unsigned r;
  asm("v_cvt_pk_bf16_f32 %0, %1, %2" : "=v"(r) : "v"(lo), "v"(hi));
  return r;
}

// ---------------- prep: Wh = h@W (fp32), WhT bf16 [bt][f][j], Wh1/Wh2 (pre-scaled by log2e)
__global__ __launch_bounds__(256) void prep_kernel(
    const float* __restrict__ h, const float* __restrict__ W,
    const float* __restrict__ a, unsigned short* __restrict__ WhT,
    float* __restrict__ Wh1, float* __restrict__ Wh2) {
  __shared__ float Ws[64][64];
  __shared__ float hs[64][64];
  __shared__ float Whs[64][65];
  const int tid = threadIdx.x;
  const int row0 = blockIdx.x * 64;   // row in flattened [B*T*N]
  const int bt = row0 >> 11;
  const int j0 = row0 & 2047;
  for (int i = tid; i < 4096; i += 256) Ws[i >> 6][i & 63] = W[i];
  for (int i = tid; i < 4096; i += 256) hs[i >> 6][i & 63] = h[(size_t)row0 * 64 + i];
  __syncthreads();
  const int f = tid & 63;
  const int rq = tid >> 6;
  float acc[16];
#pragma unroll
  for (int m = 0; m < 16; ++m) acc[m] = 0.f;
#pragma unroll 4
  for (int k = 0; k < 64; ++k) {
    const float wvv = Ws[k][f];
#pragma unroll
    for (int m = 0; m < 16; ++m) acc[m] = fmaf(hs[rq * 16 + m][k], wvv, acc[m]);
  }
#pragma unroll
  for (int m = 0; m < 16; ++m) Whs[rq * 16 + m][f] = acc[m];
  __syncthreads();
  {
    const int r = tid >> 2, q = tid & 3;
    float s1 = 0.f, s2 = 0.f;
#pragma unroll
    for (int k = 0; k < 16; ++k) {
      const float v = Whs[r][q * 16 + k];
      s1 = fmaf(v, a[q * 16 + k], s1);
      s2 = fmaf(v, a[64 + q * 16 + k], s2);
    }
    s1 += __shfl_xor(s1, 1); s1 += __shfl_xor(s1, 2);
    s2 += __shfl_xor(s2, 1); s2 += __shfl_xor(s2, 2);
    if (q == 0) {
      // pre-scale by log2(e): LeakyReLU is positively homogeneous, so
      // exp(LRelu(w1+w2)) == exp2(LRelu(log2e*w1 + log2e*w2))
      Wh1[(size_t)bt * N_ + j0 + r] = s1 * LOG2E;
      Wh2[(size_t)bt * N_ + j0 + r] = s2 * LOG2E;
    }
  }
  {
    const int ff = tid & 63, cp = tid >> 6;
#pragma unroll
    for (int cc = 0; cc < 2; ++cc) {
      const int c = cp * 2 + cc;
      short8 v;
#pragma unroll
      for (int k = 0; k < 8; ++k) v[k] = (short)f2bf(Whs[c * 8 + k][ff]);
      *(short8*)(WhT + ((size_t)bt * 64 + ff) * N_ + j0 + c * 8) = v;
    }
  }
}

// ---------------- main: softmax-over-T attention + MFMA PV (+ELU if !split)
__global__ __launch_bounds__(512) void gat_mfma(
    const unsigned short* __restrict__ WhT, const float* __restrict__ Wh1,
    const float* __restrict__ Wh2, const int* __restrict__ adj,
    float* __restrict__ out, float* __restrict__ part, const int split) {
  __shared__ unsigned short atts[2][T_][TI][JCP];  // bf16 att tiles, dbuf (36.9KB)
  __shared__ float wh2T[2][JC][T_];                // Wh2 chunk, [j][t], dbuf (4KB)
  __shared__ float wh1s[T_][TI];
  const int tid = threadIdx.x;
  int b, i0, jh, nchunk;
  if (split) {
    jh = blockIdx.x & 1;
    b = blockIdx.x >> 8;
    i0 = ((blockIdx.x >> 1) & 127) * TI;
    nchunk = N_ / JC / 2;    // 16
  } else {
    jh = 0;
    b = blockIdx.x >> 7;
    i0 = (blockIdx.x & 127) * TI;
    nchunk = N_ / JC;        // 32
  }
  const int jbase = jh * (N_ / 2);

  if (tid < T_ * TI) {
    const int t = tid >> 4, ii = tid & 15;
    wh1s[t][ii] = Wh1[(size_t)(b * T_ + t) * N_ + i0 + ii];
  }

  const int wv = tid >> 6;        // wave id == t
  const int lane = tid & 63;
  const int col = lane & 15;
  const int kg = lane >> 4;

  const int sii = tid >> 5;          // softmax i-row 0..15
  const int sjj = (tid & 31) * 2;    // softmax j-cols (sjj, sjj+1)
  const int sjL = tid & 63, stt = tid >> 6;  // wh2T staging assignment

  const unsigned short* wtb = WhT + (size_t)(b * T_ + wv) * F_ * N_;
  const float* wh2b = Wh2 + (size_t)b * T_ * N_;

  f32x4 acc[4];
#pragma unroll
  for (int nt = 0; nt < 4; ++nt) acc[nt] = {0.f, 0.f, 0.f, 0.f};

  // prologue: stage wh2T buf0 (chunk 0)
  wh2T[0][sjL][stt] = wh2b[(size_t)stt * N_ + jbase + sjL];
  __syncthreads();

  // hoist Wh1 row (chunk-invariant) into registers
  float w1r[T_];
#pragma unroll
  for (int t = 0; t < T_; ++t) w1r[t] = wh1s[t][sii];

  for (int c = 0; c < nchunk; ++c) {
    const int j0 = jbase + c * JC;
    const int buf = c & 1;
    // --- issue B-fragment global loads early
    short8 breg[4][2];
#pragma unroll
    for (int nt = 0; nt < 4; ++nt)
#pragma unroll
      for (int ks = 0; ks < 2; ++ks)
        breg[nt][ks] = *(const short8*)(wtb + (size_t)(nt * 16 + col) * N_ +
                                        j0 + ks * 32 + kg * 8);
    // --- stage next chunk's Wh2 (consumed after this chunk's barrier)
    if (c + 1 < nchunk)
      wh2T[buf ^ 1][sjL][stt] = wh2b[(size_t)stt * N_ + j0 + JC + sjL];

    // --- softmax over T for columns (sjj, sjj+1), row sii; no max pass
    {
      const int2 ad = *(const int2*)(adj + (size_t)(i0 + sii) * N_ + j0 + sjj);
      const float* wp = &wh2T[buf][sjj][0];
      const f32x4 wa0 = *(const f32x4*)(wp);       // col sjj,  t0..3
      const f32x4 wa1 = *(const f32x4*)(wp + 4);   // col sjj,  t4..7
      const f32x4 wb0 = *(const f32x4*)(wp + 8);   // col sjj+1,t0..3
      const f32x4 wb1 = *(const f32x4*)(wp + 12);  // col sjj+1,t4..7
      float e0[T_], e1[T_];
      float s0 = 0.f, s1 = 0.f;
#pragma unroll
      for (int t = 0; t < T_; ++t) {
        const float w2a = t < 4 ? wa0[t & 3] : wa1[t & 3];
        const float w2b = t < 4 ? wb0[t & 3] : wb1[t & 3];
        float x0 = w1r[t] + w2a;
        float x1 = w1r[t] + w2b;
        x0 = fmaxf(x0, 0.2f * x0);   // LeakyReLU (alpha<1, scale-commuting)
        x1 = fmaxf(x1, 0.2f * x1);
        e0[t] = __builtin_amdgcn_exp2f(x0);
        e1[t] = __builtin_amdgcn_exp2f(x1);
        s0 += e0[t];
        s1 += e1[t];
      }
      // adj==0 -> all-NEG_INF column -> softmax over t uniform 1/8:
      // fold into one fma: a = e * r + add0  with (r=0, add0=0.125)
      const float r0 = ad.x > 0 ? __builtin_amdgcn_rcpf(s0) : 0.f;
      const float r1 = ad.y > 0 ? __builtin_amdgcn_rcpf(s1) : 0.f;
      const float d0 = ad.x > 0 ? 0.f : 0.125f;
      const float d1 = ad.y > 0 ? 0.f : 0.125f;
#pragma unroll
      for (int t = 0; t < T_; ++t) {
        const float a0 = fmaf(e0[t], r0, d0);
        const float a1 = fmaf(e1[t], r1, d1);
        *(unsigned*)&atts[buf][t][sii][sjj] = cvt_pk_bf16(a0, a1);
      }
    }
    __syncthreads();
    // --- MFMA: A = att[16i x 64j], B = WhT[64f x 64j] both bf16
    const unsigned short* ab = &atts[buf][wv][col][kg * 8];
    const short8 a0 = *(const short8*)ab;
    const short8 a1 = *(const short8*)(ab + 32);
#pragma unroll
    for (int nt = 0; nt < 4; ++nt) {
      acc[nt] = __builtin_amdgcn_mfma_f32_16x16x32_bf16(a0, breg[nt][0], acc[nt], 0, 0, 0);
      acc[nt] = __builtin_amdgcn_mfma_f32_16x16x32_bf16(a1, breg[nt][1], acc[nt], 0, 0, 0);
    }
  }

  // ---- epilogue. C/D: col=lane&15, row=(lane>>4)*4+reg
  float* dst = (split && jh) ? part : out;
  float* ob = dst + ((size_t)(b * T_ + wv) * N_ + i0) * F_;
#pragma unroll
  for (int nt = 0; nt < 4; ++nt) {
#pragma unroll
    for (int r = 0; r < 4; ++r) {
      const int row = kg * 4 + r;
      const float x = acc[nt][r];
      ob[(size_t)row * F_ + nt * 16 + col] =
          split ? x : (x > 0.f ? x : expm1f(x));
    }
  }
}

// ---------------- combine partials + ELU (split mode only)
__global__ __launch_bounds__(256) void combine_elu(
    float* __restrict__ out, const float* __restrict__ part) {
  const size_t i = ((size_t)blockIdx.x * 256 + threadIdx.x) * 4;
  f32x4 o = *(const f32x4*)(out + i);
  const f32x4 p = *(const f32x4*)(part + i);
#pragma unroll
  for (int k = 0; k < 4; ++k) {
    const float x = o[k] + p[k];
    o[k] = x > 0.f ? x : expm1f(x);
  }
  *(f32x4*)(out + i) = o;
}

extern "C" void kernel_launch(void* const* d_in, const int* in_sizes, int n_in,
                              void* d_out, int out_size, void* d_ws, size_t ws_size,
                              hipStream_t stream) {
  const float* h   = (const float*)d_in[0];
  const float* W   = (const float*)d_in[1];
  const float* a   = (const float*)d_in[2];
  const int*   adj = (const int*)d_in[3];
  float* out = (float*)d_out;

  const size_t whtBytes  = (size_t)B_ * T_ * F_ * N_ * 2;    // 4MB
  const size_t vBytes    = (size_t)B_ * T_ * N_ * 4;         // 128KB
  const size_t partBytes = (size_t)B_ * T_ * N_ * F_ * 4;    // 8MB
  const size_t need = whtBytes + 2 * vBytes + partBytes;

  unsigned short* WhT = (unsigned short*)d_ws;
  float* Wh1  = (float*)((char*)d_ws + whtBytes);
  float* Wh2  = Wh1 + (size_t)B_ * T_ * N_;
  float* part = Wh2 + (size_t)B_ * T_ * N_;

  const int split = (ws_size >= need) ? 1 : 0;

  hipLaunchKernelGGL(prep_kernel, dim3(B_ * T_ * N_ / 64), dim3(256), 0, stream,
                     h, W, a, WhT, Wh1, Wh2);
  hipLaunchKernelGGL(gat_mfma, dim3(split ? 512 : 256), dim3(512), 0, stream,
                     WhT, Wh1, Wh2, adj, out, part, split);
  if (split) {
    hipLaunchKernelGGL(combine_elu, dim3(B_ * T_ * N_ * F_ / (256 * 4)), dim3(256),
                       0, stream, out, part);
  }
}